// Round 7
// baseline (41.870 us; speedup 1.0000x reference)
//
#include <hip/hip_runtime.h>

// ---------------------------------------------------------------------------
// PodNetClassifier: out[b][c] = sum_k simi*softmax_k(simi),
//   simi[b,c,k] = -max(2 - 2*dot(a_b, th_{c*10+k}), 0)  (unit vectors)
// Round 6: wave tile 32x80 -> 64x80 (BM=256). Halves register-fill L1 traffic
// (5.6 -> 3.6 B/output) and halves wave count; B fragments amortized over 4
// row-tiles. mt-pipelined: mfma(k+1) covers wr(k)'s LDS latency; acc held one
// mt at a time (~130 VGPR). Epilogue math unchanged (exp2/rcp, f32 LDS).
// ---------------------------------------------------------------------------

#define BATCH   8192
#define DIM     64
#define KPROX   10
#define NCLASS  1000
#define NCOL    (NCLASS * KPROX)   // 10000
#define NBTILE  (BATCH / 16)       // 512
#define NNTILE  (NCOL / 16)        // 625

#define BM      256                // rows per block (4 waves x 64)
#define BN      80                 // cols per block (5 mfma tiles, 8 classes)
#define NBM     (BATCH / BM)       // 32
#define NBN     (NCOL / BN)        // 125
#define CSTR    20                 // LDS words per column slab (16 rows + pad)

#define XBLKS   (NBTILE / 4)         // 128 prep blocks for x
#define TBLKS   ((NCOL + 255) / 256) // 40 prep blocks for theta

typedef __attribute__((ext_vector_type(8))) short bf16x8;
typedef __attribute__((ext_vector_type(4))) float f32x4;
typedef __attribute__((ext_vector_type(2))) float f32x2;

#define LOG2E 1.4426950408889634f
#define LN2   0.6931471805599453f

__device__ inline unsigned short f32_to_bf16(float f) {
    unsigned int u = __float_as_uint(f);
    u += 0x7FFFu + ((u >> 16) & 1u);   // round-to-nearest-even
    return (unsigned short)(u >> 16);
}

// ---- merged prep: blocks [0,128) pack x, blocks [128,168) pack theta -------
// X planes: Xf_p[(bt*64 + lane)*8 + i] = a[bt*16 + (lane&15)][p*32 + (lane>>4)*8 + i]
// TH planes: same fragment layout over proxy rows j = c*10+kk.
__global__ __launch_bounds__(256)
void prep_kernel(const float* __restrict__ x, const float* __restrict__ theta,
                 unsigned short* __restrict__ Xf0, unsigned short* __restrict__ Xf1,
                 unsigned short* __restrict__ THf0, unsigned short* __restrict__ THf1) {
    if (blockIdx.x < XBLKS) {
        int wave = threadIdx.x >> 6, lane = threadIdx.x & 63;
        int bt  = blockIdx.x * 4 + wave;
        int r16 = lane & 15, hi = lane >> 4;
        const float* src = x + (size_t)(bt * 16 + r16) * DIM + hi * 8;
        f32x4 v0 = *(const f32x4*)(src);
        f32x4 v1 = *(const f32x4*)(src + 4);
        f32x4 v2 = *(const f32x4*)(src + 32);
        f32x4 v3 = *(const f32x4*)(src + 36);
        float ss = 0.f;
        #pragma unroll
        for (int i = 0; i < 4; ++i)
            ss += v0[i]*v0[i] + v1[i]*v1[i] + v2[i]*v2[i] + v3[i]*v3[i];
        ss += __shfl_xor(ss, 16);
        ss += __shfl_xor(ss, 32);
        float sc = __builtin_amdgcn_rsqf(ss);   // norms are O(8), no eps needed
        bf16x8 p0, p1;
        #pragma unroll
        for (int i = 0; i < 4; ++i) {
            p0[i]     = (short)f32_to_bf16(v0[i] * sc);
            p0[i + 4] = (short)f32_to_bf16(v1[i] * sc);
            p1[i]     = (short)f32_to_bf16(v2[i] * sc);
            p1[i + 4] = (short)f32_to_bf16(v3[i] * sc);
        }
        ((bf16x8*)Xf0)[bt * 64 + lane] = p0;
        ((bf16x8*)Xf1)[bt * 64 + lane] = p1;
    } else {
        int tid = (blockIdx.x - XBLKS) * 256 + threadIdx.x;
        if (tid >= NCOL) return;
        int kk = tid / NCLASS, c = tid - kk * NCLASS;  // consecutive tid -> consecutive c
        const float* src = theta + kk * NCLASS + c;
        float v[DIM];
        float ss = 0.f;
        #pragma unroll
        for (int d = 0; d < DIM; ++d) {
            v[d] = src[(size_t)d * NCOL];
            ss += v[d] * v[d];
        }
        float sc = __builtin_amdgcn_rsqf(ss);
        int j = c * KPROX + kk;
        int jt = j >> 4, jr = j & 15;
        #pragma unroll
        for (int h = 0; h < 8; ++h) {      // chunk h holds d = h*8 .. h*8+7
            unsigned short* dst = (h < 4 ? THf0 : THf1)
                                + ((size_t)jt * 64 + (h & 3) * 16 + jr) * 8;
            #pragma unroll
            for (int i = 0; i < 8; ++i)
                dst[i] = f32_to_bf16(v[h * 8 + i] * sc);
        }
    }
}

// ---- main: 64x80 wave tiles, mt-pipelined MFMA + fused softmax -------------
__global__ __launch_bounds__(256, 3)
void podnet_main(const unsigned short* __restrict__ Xf0,
                 const unsigned short* __restrict__ Xf1,
                 const unsigned short* __restrict__ THf0,
                 const unsigned short* __restrict__ THf1,
                 float* __restrict__ out) {
    __shared__ float S[4][BN][CSTR];   // 25.6 KB, wave-private slabs

    int bm = blockIdx.x / NBN, bn = blockIdx.x % NBN;
    int wave = threadIdx.x >> 6, lane = threadIdx.x & 63;

    const bf16x8* xf0 = (const bf16x8*)Xf0;
    const bf16x8* xf1 = (const bf16x8*)Xf1;
    const bf16x8* tf0 = (const bf16x8*)THf0;
    const bf16x8* tf1 = (const bf16x8*)THf1;

    int ab = (bm * 16 + wave * 4) * 64 + lane;  // 4 row-tiles per wave
    int bb = (bn * 5) * 64 + lane;              // 5 col-tiles per block

    // ---- all 18 loads issued back-to-back, pinned before any compute ------
    bf16x8 a0[4], a1[4], b0[5], b1[5];
    #pragma unroll
    for (int k = 0; k < 4; ++k) { a0[k] = xf0[ab + k * 64]; a1[k] = xf1[ab + k * 64]; }
    #pragma unroll
    for (int t = 0; t < 5; ++t) { b0[t] = tf0[bb + t * 64]; b1[t] = tf1[bb + t * 64]; }
    __builtin_amdgcn_sched_barrier(0);

    int r16 = lane & 15, hi = lane >> 4;   // writer coords
    int rp  = lane >> 3, g  = lane & 7;    // reader coords: row-pair, class

    size_t orow_base = (size_t)bm * BM + wave * 64 + rp * 2;
    float* obase = out + bn * 8 + g;

    // mt=0 MFMAs
    f32x4 acc_c[5], acc_n[5];
    #pragma unroll
    for (int t = 0; t < 5; ++t) {
        f32x4 c = {0.f, 0.f, 0.f, 0.f};
        c = __builtin_amdgcn_mfma_f32_16x16x32_bf16(a0[0], b0[t], c, 0, 0, 0);
        c = __builtin_amdgcn_mfma_f32_16x16x32_bf16(a1[0], b1[t], c, 0, 0, 0);
        acc_c[t] = c;
    }

    #pragma unroll
    for (int k = 0; k < 4; ++k) {
        // scores(k) -> LDS, pre-scaled by log2e: y = (2s-2)*log2e, y <= 0
        #pragma unroll
        for (int t = 0; t < 5; ++t) {
            f32x4 s;
            #pragma unroll
            for (int r = 0; r < 4; ++r)
                s[r] = fminf(fmaf(acc_c[t][r], 2.0f * LOG2E, -2.0f * LOG2E), 0.f);
            *(f32x4*)&S[wave][t * 16 + r16][hi * 4] = s;
        }
        // next mt's MFMAs cover the LDS write latency
        if (k < 3) {
            #pragma unroll
            for (int t = 0; t < 5; ++t) {
                f32x4 c = {0.f, 0.f, 0.f, 0.f};
                c = __builtin_amdgcn_mfma_f32_16x16x32_bf16(a0[k + 1], b0[t], c, 0, 0, 0);
                c = __builtin_amdgcn_mfma_f32_16x16x32_bf16(a1[k + 1], b1[t], c, 0, 0, 0);
                acc_n[t] = c;
            }
        }
        // softmax over 10: lane owns (row-pair rp, class g); packed f32x2 math
        {
            f32x2 ps = {0.f, 0.f}, ws = {0.f, 0.f};
            #pragma unroll
            for (int i = 0; i < KPROX; ++i) {
                f32x2 v = *(const f32x2*)&S[wave][g * 10 + i][rp * 2];
                f32x2 e; e.x = exp2f(v.x); e.y = exp2f(v.y);  // y in [-5.77,0]
                ps += e;
                ws += v * e;
            }
            float o0 = ws.x * __builtin_amdgcn_rcpf(ps.x) * LN2;
            float o1 = ws.y * __builtin_amdgcn_rcpf(ps.y) * LN2;
            float* op = obase + (orow_base + k * 16) * NCLASS;
            __builtin_nontemporal_store(o0, op);
            __builtin_nontemporal_store(o1, op + NCLASS);
        }
        #pragma unroll
        for (int t = 0; t < 5; ++t) acc_c[t] = acc_n[t];
    }
}

extern "C" void kernel_launch(void* const* d_in, const int* in_sizes, int n_in,
                              void* d_out, int out_size, void* d_ws, size_t ws_size,
                              hipStream_t stream) {
    const float* x     = (const float*)d_in[0];   // (8192, 64)
    const float* theta = (const float*)d_in[1];   // (64, 10, 1000)
    float* out = (float*)d_out;                   // (8192, 1000) f32

    unsigned short* Xf0 = (unsigned short*)d_ws;       // 512 KB each X plane
    unsigned short* Xf1 = Xf0 + (size_t)NBTILE * 512;
    unsigned short* Tf0 = Xf1 + (size_t)NBTILE * 512;  // 640 KB each TH plane
    unsigned short* Tf1 = Tf0 + (size_t)NNTILE * 512;

    prep_kernel<<<XBLKS + TBLKS, 256, 0, stream>>>(x, theta, Xf0, Xf1, Tf0, Tf1);
    podnet_main<<<NBM * NBN, 256, 0, stream>>>(Xf0, Xf1, Tf0, Tf1, out);
}